// Round 15
// baseline (157.084 us; speedup 1.0000x reference)
//
#include <hip/hip_runtime.h>

#define CELLS 81
#define ND 9
#define HID 100
#define NP 52    // padded unit-pairs: 50 real + 2 zero
#define PPW 13   // pairs per wave (4 waves x 13 = 52)
#define NREG 8   // W2 pairs persisted in VGPRs per wave (rest via LDS)

typedef float v2f __attribute__((ext_vector_type(2)));

#define TROW 106                      // floats per T row: 52*2 + 2 pad (bank spread)
#define T_SZ (9 * 8 * TROW)           // 7632 floats: [dc][mask][pair]{u0,u1}
#define W1P_OFF T_SZ                  // 7632
#define W1P_SZ (9 * NP * 8)           // 3744: [d][pair]{A0,A1,B0,B1,C0,C1,0,0} (init)
#define W2P_OFF (W1P_OFF + W1P_SZ)    // 11376
#define W2P_SZ (NP * 20)              // 1040: [pair]{d0u0,d0u1,...,d8u0,d8u1,0,0}
#define CNT_OFF (W2P_OFF + W2P_SZ)    // 12416 (int words)
#define ORD_OFF (CNT_OFF + 4)
#define BIGSLOTS 64
#define SPILLSLOTS 8
#define NBLK (BIGSLOTS + 512 + SPILLSLOTS)   // 584 solver blocks

// One prolog kernel: packs all weight tables (spread over blocks) and does
// per-board empty-count + atomic two-region pairing into order[].
// order[] pre-memset to -1, cnts to 0 (hipMemsetAsync, graph-safe).
__global__ __launch_bounds__(64) void prep_kernel(
    const float* __restrict__ x_all,
    const float* __restrict__ W1, const float* __restrict__ W2,
    float* __restrict__ ws, int* __restrict__ cnts, int* __restrict__ order,
    int nBoards)
{
    const int b = blockIdx.x, t = threadIdx.x;
    const int gid = b * 64 + t;

    // ---- table build, parallel across blocks ----
    if (gid < T_SZ) {
        int row = gid / TROW, off = gid - row * TROW;
        float v = 0.f;
        if (off < 104) {
            int pair = off >> 1, u = 2 * pair + (off & 1);
            if (pair < 50) {
                int dc = row >> 3, m = row & 7;
                if (m & 1) v += W1[u*27 + dc];
                if (m & 2) v += W1[u*27 + 9 + dc];
                if (m & 4) v += W1[u*27 + 18 + dc];
            }
        }
        ws[gid] = v;
    } else if (gid < W2P_OFF) {
        int f = gid - W1P_OFF;
        int i = f >> 3, k = f & 7;
        int d = i / NP, j = i - d * NP;
        float v = 0.f;
        if (j < 50 && k < 6) {
            int u = 2 * j + (k & 1);
            v = W1[u*27 + (k >> 1) * 9 + d];
        }
        ws[gid] = v;
    } else if (gid < CNT_OFF) {
        int f = gid - W2P_OFF;
        int j = f / 20, k = f - j * 20;
        float v = 0.f;
        if (j < 50 && k < 18) {
            int d = k >> 1, u = 2 * j + (k & 1);
            v = W2[d*HID + u];
        }
        ws[gid] = v;
    }

    if (b >= nBoards) return;

    // ---- per-board empty count ----
    const float* xb = x_all + (size_t)b * (CELLS * ND);
    float mx = 0.f;
    #pragma unroll
    for (int d = 0; d < ND; ++d) mx = fmaxf(mx, xb[t*ND + d]);
    bool e1 = (mx < 0.5f);
    bool e2 = false;
    if (t < CELLS - 64) {
        float m2 = 0.f;
        #pragma unroll
        for (int d = 0; d < ND; ++d) m2 = fmaxf(m2, xb[(64+t)*ND + d]);
        e2 = (m2 < 0.5f);
    }
    unsigned long long m1 = __ballot(e1), m2b = __ballot(e2);
    if (t == 0) {
        int ne = __popcll(m1) + __popcll(m2b);
        if (ne > 32) {                       // big: own joined block, region [0,64)+spill
            int p = atomicAdd(&cnts[0], 1);
            int blk = (p < BIGSLOTS) ? p : (BIGSLOTS + 512 + (p - BIGSLOTS));
            if (blk < NBLK) { order[2*blk] = b; order[2*blk + 1] = b; }
        } else {                             // small: pair in region [64, 576)
            int p = atomicAdd(&cnts[1], 1);
            int blk = BIGSLOTS + (p >> 1);
            order[2*blk + (p & 1)] = b;
        }
    }
}

// 2 blocks/CU, 2 waves/EU (VGPR cap 256): W2 for NREG pairs in registers.
__global__ __launch_bounds__(256, 2) void sudoku_kernel(
    const float* __restrict__ x_all,
    const float* __restrict__ ws,
    const int* __restrict__ order,
    float* __restrict__ out, int nBoards)
{
    const int tid = threadIdx.x;      // 4 waves x 13 pairs
    const int wv  = tid >> 6;
    const int lw  = tid & 63;
    const int h   = lw >> 5;          // 32-lane segment within wave
    const int jbase = wv * PPW;

    const int s0  = order[2 * blockIdx.x];
    const int s1r = order[2 * blockIdx.x + 1];
    if (s0 < 0) return;
    const int s1 = (s1r < 0) ? s0 : s1r;
    const bool joined = (s0 == s1);   // one 64-lane board (big or lone small)
    const int myBoard = h ? s1 : s0;
    const int idx = joined ? 0 : h;   // cnt/digit slot

    float* pom = out + (size_t)myBoard * (CELLS * ND);

    __shared__ __align__(16) float tS[T_SZ];         // 30528 B combo table
    __shared__ __align__(16) float w2s[W2P_SZ];      // 4160 B
    __shared__ v2f parts[2][4][5][64];               // 20480 B dbuf partials
    __shared__ float cnt[2][3 * 81];                 // 1944 B
    __shared__ int   digit[2][CELLS];                // 648 B

    // ---- stage T + W2 to LDS, zero counts ----
    for (int i = tid; i < T_SZ / 4; i += 256)
        ((float4*)tS)[i] = ((const float4*)ws)[i];
    for (int i = tid; i < W2P_SZ / 4; i += 256)
        ((float4*)w2s)[i] = ((const float4*)(ws + W2P_OFF))[i];
    for (int i = tid; i < 2 * 243; i += 256) (&cnt[0][0])[i] = 0.f;
    __syncthreads();

    // ---- W2 for first NREG own pairs in regs, loaded from GLOBAL (uniform)
    //      so the compiler can't rematerialize them as in-loop LDS reads ----
    const float* w2g = ws + W2P_OFF;
    float w2reg[NREG][18];
    #pragma unroll
    for (int j = 0; j < NREG; ++j) {
        #pragma unroll
        for (int k = 0; k < 18; ++k) w2reg[j][k] = w2g[(jbase + j) * 20 + k];
    }

    // ---- per-slot digit scan + counts + po init ----
    {
        const int slot = (tid < 128) ? 0 : 1;
        const int t = (tid < 128) ? tid : tid - 128;
        const bool doSlot = (slot == 0) || !joined;
        const int bd = slot ? s1 : s0;
        const float* xb = x_all + (size_t)bd * (CELLS * ND);
        float* pob = out + (size_t)bd * (CELLS * ND);
        if (doSlot) {
            if (t < CELLS) {
                int dig = -1;
                #pragma unroll
                for (int d = 0; d < ND; ++d)
                    if (dig < 0 && xb[t*ND + d] > 0.5f) dig = d;
                digit[slot][t] = dig;
                if (dig >= 0) {
                    int r = t/9, c = t%9, b = (r/3)*3 + c/3;
                    atomicAdd(&cnt[slot][r*9 + dig], 1.f);
                    atomicAdd(&cnt[slot][81 + c*9 + dig], 1.f);
                    atomicAdd(&cnt[slot][162 + b*9 + dig], 1.f);
                }
            }
            for (int i = t; i < CELLS * ND; i += 128) pob[i] = xb[i];
        }
    }
    __syncthreads();

    // ---- rank -> cell via digit scan; ne for both slots ----
    const int rank = joined ? lw : (lw & 31);
    int myq = 127;
    int ne0 = 0, ne1 = 0;
    for (int q = 0; q < CELLS; ++q)
        if (digit[0][q] < 0) { if (idx == 0 && ne0 == rank) myq = q; ++ne0; }
    if (!joined) {
        for (int q = 0; q < CELLS; ++q)
            if (digit[1][q] < 0) { if (idx == 1 && ne1 == rank) myq = q; ++ne1; }
    } else ne1 = ne0;
    if (ne0 > 64) ne0 = 64;
    if (ne1 > 64) ne1 = 64;
    const int ne_mine = idx ? ne1 : ne0;
    const int itMax = max(ne0, ne1);
    bool active = (rank < ne_mine);

    const int myr = (myq < 81) ? myq / 9 : 0;
    const int myc = (myq < 81) ? myq % 9 : 0;
    const int myb = (myr / 3) * 3 + myc / 3;

    // ---- z init: 27 counts in regs; packed W1 from GLOBAL (uniform, one-time) ----
    float crr[9], ccc[9], cbb[9];
    #pragma unroll
    for (int j = 0; j < 9; ++j) {
        crr[j] = cnt[idx][myr*9 + j];
        ccc[j] = cnt[idx][81 + myc*9 + j];
        cbb[j] = cnt[idx][162 + myb*9 + j];
    }
    const float* w1g = ws + W1P_OFF;
    v2f z2[PPW];
    #pragma unroll
    for (int j = 0; j < PPW; ++j) {
        v2f a = (v2f){0.f, 0.f};
        #pragma unroll
        for (int d = 0; d < 9; ++d) {
            const float* p = &w1g[(d*NP + jbase + j) * 8];
            float4 ab = *(const float4*)p;
            v2f Cv = *(const v2f*)(p + 4);
            v2f Av = (v2f){ab.x, ab.y}, Bv = (v2f){ab.z, ab.w};
            a += crr[d]*Av + ccc[d]*Bv + cbb[d]*Cv;
        }
        z2[j] = a;
    }

    int dc = 0, mym = 0;     // it=0: mask 0 -> T row is all zeros
    float pfin[ND];

    // ---- solve loop: 1 barrier/iter; z-delta = one b64 read + pk-add ----
    for (int it = 0; it < itMax; ++it) {
        const float* tT = &tS[(dc*8 + mym) * TROW + jbase*2];   // per-lane addr

        v2f acc2[ND];
        #pragma unroll
        for (int d = 0; d < ND; ++d) acc2[d] = (v2f){0.f, 0.f};

        #pragma unroll
        for (int j = 0; j < PPW; ++j) {
            v2f dz = *(const v2f*)&tT[j*2];
            v2f zv = z2[j] + dz;
            z2[j] = zv;
            v2f hh;
            hh.x = fmaxf(zv.x, 0.f);
            hh.y = fmaxf(zv.y, 0.f);
            if (j < NREG) {
                #pragma unroll
                for (int d = 0; d < ND; ++d)
                    acc2[d] += hh * (v2f){w2reg[j][2*d], w2reg[j][2*d + 1]};
            } else {
                const float* qq = &w2s[(jbase + j) * 20];
                float4 w01 = *(const float4*)qq;
                float4 w23 = *(const float4*)(qq + 4);
                float4 w45 = *(const float4*)(qq + 8);
                float4 w67 = *(const float4*)(qq + 12);
                v2f w8 = *(const v2f*)(qq + 16);
                acc2[0] += hh * (v2f){w01.x, w01.y};
                acc2[1] += hh * (v2f){w01.z, w01.w};
                acc2[2] += hh * (v2f){w23.x, w23.y};
                acc2[3] += hh * (v2f){w23.z, w23.w};
                acc2[4] += hh * (v2f){w45.x, w45.y};
                acc2[5] += hh * (v2f){w45.z, w45.w};
                acc2[6] += hh * (v2f){w67.x, w67.y};
                acc2[7] += hh * (v2f){w67.z, w67.w};
                acc2[8] += hh * w8;
            }
        }

        // horizontal reduce, publish as v2f pairs, combine in fixed wave order
        float accH[10];
        #pragma unroll
        for (int d = 0; d < ND; ++d) accH[d] = acc2[d].x + acc2[d].y;
        accH[9] = 0.f;
        const int buf = it & 1;
        #pragma unroll
        for (int k = 0; k < 5; ++k)
            parts[buf][wv][k][lw] = (v2f){accH[2*k], accH[2*k + 1]};
        __syncthreads();

        float acc[ND];
        #pragma unroll
        for (int k = 0; k < 5; ++k) {
            v2f s = parts[buf][0][k][lw];
            #pragma unroll
            for (int ow = 1; ow < 4; ++ow) s += parts[buf][ow][k][lw];
            acc[2*k] = s.x;
            if (k < 4) acc[2*k + 1] = s.y;
        }

        // softmax + per-cell best digit (strict >: first max)
        float m9 = fmaxf(fmaxf(fmaxf(acc[0],acc[1]), fmaxf(acc[2],acc[3])),
                         fmaxf(fmaxf(acc[4],acc[5]), fmaxf(acc[6],acc[7])));
        m9 = fmaxf(m9, acc[8]);
        float s = 0.f;
        #pragma unroll
        for (int d = 0; d < ND; ++d) { acc[d] = __expf(acc[d] - m9); s += acc[d]; }
        float inv = 1.f / s;
        float bv = -1.f; int bd = 0;
        #pragma unroll
        for (int d = 0; d < ND; ++d) {
            acc[d] *= inv;
            if (acc[d] > bv) { bv = acc[d]; bd = d; }
        }

        // per-segment winner: butterfly within 32 lanes (+1 round if joined)
        float bvv = active ? bv : -1.f;
        float vmax = bvv;
        #pragma unroll
        for (int off = 16; off >= 1; off >>= 1)
            vmax = fmaxf(vmax, __shfl_xor(vmax, off));
        if (joined) vmax = fmaxf(vmax, __shfl_xor(vmax, 32));
        const unsigned long long segMask =
            joined ? ~0ull : (h ? 0xFFFFFFFF00000000ull : 0x00000000FFFFFFFFull);
        unsigned long long msk = __ballot(active && (bvv == vmax)) & segMask;
        const bool valid = (msk != 0);
        int wl = valid ? (__ffsll(msk) - 1) : 0;   // lowest lane = lowest q
        int qw = __shfl(myq, wl);
        int dwn = __shfl(bd, wl);

        if (active && valid && myq == qw) {
            #pragma unroll
            for (int d = 0; d < ND; ++d) pfin[d] = acc[d];
            if (wv == 0) digit[idx][myq] = dwn;
            active = false;
        }
        const int pr = qw/9, pcc = qw%9, pb = (pr/3)*3 + pcc/3;
        mym = valid ? (((myr == pr) ? 1 : 0) | ((myc == pcc) ? 2 : 0)
                     | ((myb == pb) ? 4 : 0)) : 0;
        if (valid) dc = dwn;
    }

    // ---- outputs ----
    __syncthreads();
    if (wv == 0 && myq < 81) {
        #pragma unroll
        for (int d = 0; d < ND; ++d) pom[myq*ND + d] = pfin[d];
    }
    {
        const int slot = (tid < 128) ? 0 : 1;
        const int t = (tid < 128) ? tid : tid - 128;
        const bool doSlot = (slot == 0) || !joined;
        const int bd2 = slot ? s1 : s0;
        float* fob = out + (size_t)nBoards * (CELLS * ND) + (size_t)bd2 * (CELLS * ND);
        if (doSlot) {
            for (int i = t; i < CELLS * ND; i += 128) {
                int q = i / ND, d = i - q * ND;
                fob[i] = (digit[slot][q] == d) ? 1.f : 0.f;
            }
        }
    }
}

extern "C" void kernel_launch(void* const* d_in, const int* in_sizes, int n_in,
                              void* d_out, int out_size, void* d_ws, size_t ws_size,
                              hipStream_t stream) {
    const float* x  = (const float*)d_in[0];
    // d_in[1] is the constraint mask c — structurally known, not needed.
    const float* W1 = (const float*)d_in[2];
    const float* W2 = (const float*)d_in[3];
    float* out = (float*)d_out;
    float* ws  = (float*)d_ws;
    int nBoards = in_sizes[0] / (CELLS * ND);
    int* cnts   = (int*)ws + CNT_OFF;
    int* ordArr = (int*)ws + ORD_OFF;
    hipMemsetAsync(cnts, 0, 2 * sizeof(int), stream);
    hipMemsetAsync(ordArr, 0xFF, 2 * NBLK * sizeof(int), stream);
    int prepBlocks = (nBoards > 194) ? nBoards : 194;   // tables need 194 blocks
    prep_kernel<<<prepBlocks, 64, 0, stream>>>(x, W1, W2, ws, cnts, ordArr, nBoards);
    sudoku_kernel<<<NBLK, 256, 0, stream>>>(x, ws, ordArr, out, nBoards);
}

// Round 16
// 155.605 us; speedup vs baseline: 1.0095x; 1.0095x over previous
//
#include <hip/hip_runtime.h>

#define CELLS 81
#define ND 9
#define HID 100
#define NP 52    // padded unit-pairs: 50 real + 2 zero
#define PPW 13   // pairs per wave (4 waves x 13 = 52)
#define NREG 8   // W2 pairs persisted in VGPRs per wave (rest via LDS)

typedef float v2f __attribute__((ext_vector_type(2)));

#define TROW 106                      // floats per T row: 52*2 + 2 pad (bank spread)
#define T_SZ (9 * 8 * TROW)           // 7632 floats: [dc][mask][pair]{u0,u1}
#define W1P_OFF T_SZ                  // 7632
#define W1P_SZ (9 * NP * 8)           // 3744: [d][pair]{A0,A1,B0,B1,C0,C1,0,0} (init)
#define W2P_OFF (W1P_OFF + W1P_SZ)    // 11376
#define W2P_SZ (NP * 20)              // 1040: [pair]{d0u0,d0u1,...,d8u0,d8u1,0,0}
#define CNT_OFF (W2P_OFF + W2P_SZ)    // 12416 (int words)
#define ORD_OFF (CNT_OFF + 4)
#define BIGSLOTS 64
#define SPILLSLOTS 8
#define NBLK (BIGSLOTS + 512 + SPILLSLOTS)   // 584 solver blocks

// One prolog kernel: packs all weight tables (spread over blocks) and does
// per-board empty-count + atomic two-region pairing into order[].
// order[] pre-memset to -1, cnts to 0 (hipMemsetAsync, graph-safe).
__global__ __launch_bounds__(64) void prep_kernel(
    const float* __restrict__ x_all,
    const float* __restrict__ W1, const float* __restrict__ W2,
    float* __restrict__ ws, int* __restrict__ cnts, int* __restrict__ order,
    int nBoards)
{
    const int b = blockIdx.x, t = threadIdx.x;
    const int gid = b * 64 + t;

    // ---- table build, parallel across blocks ----
    if (gid < T_SZ) {
        int row = gid / TROW, off = gid - row * TROW;
        float v = 0.f;
        if (off < 104) {
            int pair = off >> 1, u = 2 * pair + (off & 1);
            if (pair < 50) {
                int dc = row >> 3, m = row & 7;
                if (m & 1) v += W1[u*27 + dc];
                if (m & 2) v += W1[u*27 + 9 + dc];
                if (m & 4) v += W1[u*27 + 18 + dc];
            }
        }
        ws[gid] = v;
    } else if (gid < W2P_OFF) {
        int f = gid - W1P_OFF;
        int i = f >> 3, k = f & 7;
        int d = i / NP, j = i - d * NP;
        float v = 0.f;
        if (j < 50 && k < 6) {
            int u = 2 * j + (k & 1);
            v = W1[u*27 + (k >> 1) * 9 + d];
        }
        ws[gid] = v;
    } else if (gid < CNT_OFF) {
        int f = gid - W2P_OFF;
        int j = f / 20, k = f - j * 20;
        float v = 0.f;
        if (j < 50 && k < 18) {
            int d = k >> 1, u = 2 * j + (k & 1);
            v = W2[d*HID + u];
        }
        ws[gid] = v;
    }

    if (b >= nBoards) return;

    // ---- per-board empty count ----
    const float* xb = x_all + (size_t)b * (CELLS * ND);
    float mx = 0.f;
    #pragma unroll
    for (int d = 0; d < ND; ++d) mx = fmaxf(mx, xb[t*ND + d]);
    bool e1 = (mx < 0.5f);
    bool e2 = false;
    if (t < CELLS - 64) {
        float m2 = 0.f;
        #pragma unroll
        for (int d = 0; d < ND; ++d) m2 = fmaxf(m2, xb[(64+t)*ND + d]);
        e2 = (m2 < 0.5f);
    }
    unsigned long long m1 = __ballot(e1), m2b = __ballot(e2);
    if (t == 0) {
        int ne = __popcll(m1) + __popcll(m2b);
        if (ne > 32) {                       // big: own joined block, region [0,64)+spill
            int p = atomicAdd(&cnts[0], 1);
            int blk = (p < BIGSLOTS) ? p : (BIGSLOTS + 512 + (p - BIGSLOTS));
            if (blk < NBLK) { order[2*blk] = b; order[2*blk + 1] = b; }
        } else {                             // small: pair in region [64, 576)
            int p = atomicAdd(&cnts[1], 1);
            int blk = BIGSLOTS + (p >> 1);
            order[2*blk + (p & 1)] = b;
        }
    }
}

// 2 blocks/CU, 2 waves/EU (VGPR cap 256): W2 for NREG pairs in registers
// (loaded from LDS -- R15 post-mortem: loading from global makes the
// compiler rematerialize them as in-loop GLOBAL loads, ~200cy each, -38%).
__global__ __launch_bounds__(256, 2) void sudoku_kernel(
    const float* __restrict__ x_all,
    const float* __restrict__ ws,
    const int* __restrict__ order,
    float* __restrict__ out, int nBoards)
{
    const int tid = threadIdx.x;      // 4 waves x 13 pairs
    const int wv  = tid >> 6;
    const int lw  = tid & 63;
    const int h   = lw >> 5;          // 32-lane segment within wave
    const int jbase = wv * PPW;

    const int s0  = order[2 * blockIdx.x];
    const int s1r = order[2 * blockIdx.x + 1];
    if (s0 < 0) return;
    const int s1 = (s1r < 0) ? s0 : s1r;
    const bool joined = (s0 == s1);   // one 64-lane board (big or lone small)
    const int myBoard = h ? s1 : s0;
    const int idx = joined ? 0 : h;   // cnt/digit slot

    float* pom = out + (size_t)myBoard * (CELLS * ND);

    __shared__ __align__(16) float tS[T_SZ];         // 30528 B combo table
    __shared__ __align__(16) float w2s[W2P_SZ];      // 4160 B
    __shared__ v2f parts[2][4][5][64];               // 20480 B dbuf partials
    __shared__ float cnt[2][3 * 81];                 // 1944 B
    __shared__ int   digit[2][CELLS];                // 648 B

    // ---- stage T + W2 to LDS, zero counts ----
    for (int i = tid; i < T_SZ / 4; i += 256)
        ((float4*)tS)[i] = ((const float4*)ws)[i];
    for (int i = tid; i < W2P_SZ / 4; i += 256)
        ((float4*)w2s)[i] = ((const float4*)(ws + W2P_OFF))[i];
    for (int i = tid; i < 2 * 243; i += 256) (&cnt[0][0])[i] = 0.f;
    __syncthreads();

    // ---- W2 for first NREG own pairs in regs, from LDS (R13-proven) ----
    float w2reg[NREG][18];
    #pragma unroll
    for (int j = 0; j < NREG; ++j) {
        const float* qq = &w2s[(jbase + j) * 20];
        #pragma unroll
        for (int k = 0; k < 18; ++k) w2reg[j][k] = qq[k];
    }

    // ---- per-slot digit scan + counts + po init ----
    {
        const int slot = (tid < 128) ? 0 : 1;
        const int t = (tid < 128) ? tid : tid - 128;
        const bool doSlot = (slot == 0) || !joined;
        const int bd = slot ? s1 : s0;
        const float* xb = x_all + (size_t)bd * (CELLS * ND);
        float* pob = out + (size_t)bd * (CELLS * ND);
        if (doSlot) {
            if (t < CELLS) {
                int dig = -1;
                #pragma unroll
                for (int d = 0; d < ND; ++d)
                    if (dig < 0 && xb[t*ND + d] > 0.5f) dig = d;
                digit[slot][t] = dig;
                if (dig >= 0) {
                    int r = t/9, c = t%9, b = (r/3)*3 + c/3;
                    atomicAdd(&cnt[slot][r*9 + dig], 1.f);
                    atomicAdd(&cnt[slot][81 + c*9 + dig], 1.f);
                    atomicAdd(&cnt[slot][162 + b*9 + dig], 1.f);
                }
            }
            for (int i = t; i < CELLS * ND; i += 128) pob[i] = xb[i];
        }
    }
    __syncthreads();

    // ---- rank -> cell via digit scan; ne for both slots ----
    const int rank = joined ? lw : (lw & 31);
    int myq = 127;
    int ne0 = 0, ne1 = 0;
    for (int q = 0; q < CELLS; ++q)
        if (digit[0][q] < 0) { if (idx == 0 && ne0 == rank) myq = q; ++ne0; }
    if (!joined) {
        for (int q = 0; q < CELLS; ++q)
            if (digit[1][q] < 0) { if (idx == 1 && ne1 == rank) myq = q; ++ne1; }
    } else ne1 = ne0;
    if (ne0 > 64) ne0 = 64;
    if (ne1 > 64) ne1 = 64;
    const int ne_mine = idx ? ne1 : ne0;
    const int itMax = max(ne0, ne1);
    bool active = (rank < ne_mine);

    const int myr = (myq < 81) ? myq / 9 : 0;
    const int myc = (myq < 81) ? myq % 9 : 0;
    const int myb = (myr / 3) * 3 + myc / 3;

    // ---- z init: 27 counts in regs; packed W1 from GLOBAL (uniform, one-time) ----
    float crr[9], ccc[9], cbb[9];
    #pragma unroll
    for (int j = 0; j < 9; ++j) {
        crr[j] = cnt[idx][myr*9 + j];
        ccc[j] = cnt[idx][81 + myc*9 + j];
        cbb[j] = cnt[idx][162 + myb*9 + j];
    }
    const float* w1g = ws + W1P_OFF;
    v2f z2[PPW];
    #pragma unroll
    for (int j = 0; j < PPW; ++j) {
        v2f a = (v2f){0.f, 0.f};
        #pragma unroll
        for (int d = 0; d < 9; ++d) {
            const float* p = &w1g[(d*NP + jbase + j) * 8];
            float4 ab = *(const float4*)p;
            v2f Cv = *(const v2f*)(p + 4);
            v2f Av = (v2f){ab.x, ab.y}, Bv = (v2f){ab.z, ab.w};
            a += crr[d]*Av + ccc[d]*Bv + cbb[d]*Cv;
        }
        z2[j] = a;
    }

    int dc = 0, mym = 0;     // it=0: mask 0 -> T row is all zeros
    float pfin[ND];

    // ---- solve loop: 1 barrier/iter; z-delta = one b64 read + pk-add ----
    for (int it = 0; it < itMax; ++it) {
        const float* tT = &tS[(dc*8 + mym) * TROW + jbase*2];   // per-lane addr

        v2f acc2[ND];
        #pragma unroll
        for (int d = 0; d < ND; ++d) acc2[d] = (v2f){0.f, 0.f};

        #pragma unroll
        for (int j = 0; j < PPW; ++j) {
            v2f dz = *(const v2f*)&tT[j*2];
            v2f zv = z2[j] + dz;
            z2[j] = zv;
            v2f hh;
            hh.x = fmaxf(zv.x, 0.f);
            hh.y = fmaxf(zv.y, 0.f);
            if (j < NREG) {
                #pragma unroll
                for (int d = 0; d < ND; ++d)
                    acc2[d] += hh * (v2f){w2reg[j][2*d], w2reg[j][2*d + 1]};
            } else {
                const float* qq = &w2s[(jbase + j) * 20];
                float4 w01 = *(const float4*)qq;
                float4 w23 = *(const float4*)(qq + 4);
                float4 w45 = *(const float4*)(qq + 8);
                float4 w67 = *(const float4*)(qq + 12);
                v2f w8 = *(const v2f*)(qq + 16);
                acc2[0] += hh * (v2f){w01.x, w01.y};
                acc2[1] += hh * (v2f){w01.z, w01.w};
                acc2[2] += hh * (v2f){w23.x, w23.y};
                acc2[3] += hh * (v2f){w23.z, w23.w};
                acc2[4] += hh * (v2f){w45.x, w45.y};
                acc2[5] += hh * (v2f){w45.z, w45.w};
                acc2[6] += hh * (v2f){w67.x, w67.y};
                acc2[7] += hh * (v2f){w67.z, w67.w};
                acc2[8] += hh * w8;
            }
        }

        // horizontal reduce, publish as v2f pairs, combine in fixed wave order
        float accH[10];
        #pragma unroll
        for (int d = 0; d < ND; ++d) accH[d] = acc2[d].x + acc2[d].y;
        accH[9] = 0.f;
        const int buf = it & 1;
        #pragma unroll
        for (int k = 0; k < 5; ++k)
            parts[buf][wv][k][lw] = (v2f){accH[2*k], accH[2*k + 1]};
        __syncthreads();

        float acc[ND];
        #pragma unroll
        for (int k = 0; k < 5; ++k) {
            v2f s = parts[buf][0][k][lw];
            #pragma unroll
            for (int ow = 1; ow < 4; ++ow) s += parts[buf][ow][k][lw];
            acc[2*k] = s.x;
            if (k < 4) acc[2*k + 1] = s.y;
        }

        // softmax + per-cell best digit (strict >: first max)
        float m9 = fmaxf(fmaxf(fmaxf(acc[0],acc[1]), fmaxf(acc[2],acc[3])),
                         fmaxf(fmaxf(acc[4],acc[5]), fmaxf(acc[6],acc[7])));
        m9 = fmaxf(m9, acc[8]);
        float s = 0.f;
        #pragma unroll
        for (int d = 0; d < ND; ++d) { acc[d] = __expf(acc[d] - m9); s += acc[d]; }
        float inv = 1.f / s;
        float bv = -1.f; int bd = 0;
        #pragma unroll
        for (int d = 0; d < ND; ++d) {
            acc[d] *= inv;
            if (acc[d] > bv) { bv = acc[d]; bd = d; }
        }

        // per-segment winner: butterfly within 32 lanes (+1 round if joined)
        float bvv = active ? bv : -1.f;
        float vmax = bvv;
        #pragma unroll
        for (int off = 16; off >= 1; off >>= 1)
            vmax = fmaxf(vmax, __shfl_xor(vmax, off));
        if (joined) vmax = fmaxf(vmax, __shfl_xor(vmax, 32));
        const unsigned long long segMask =
            joined ? ~0ull : (h ? 0xFFFFFFFF00000000ull : 0x00000000FFFFFFFFull);
        unsigned long long msk = __ballot(active && (bvv == vmax)) & segMask;
        const bool valid = (msk != 0);
        int wl = valid ? (__ffsll(msk) - 1) : 0;   // lowest lane = lowest q
        int qw = __shfl(myq, wl);
        int dwn = __shfl(bd, wl);

        if (active && valid && myq == qw) {
            #pragma unroll
            for (int d = 0; d < ND; ++d) pfin[d] = acc[d];
            if (wv == 0) digit[idx][myq] = dwn;
            active = false;
        }
        const int pr = qw/9, pcc = qw%9, pb = (pr/3)*3 + pcc/3;
        mym = valid ? (((myr == pr) ? 1 : 0) | ((myc == pcc) ? 2 : 0)
                     | ((myb == pb) ? 4 : 0)) : 0;
        if (valid) dc = dwn;
    }

    // ---- outputs ----
    __syncthreads();
    if (wv == 0 && myq < 81) {
        #pragma unroll
        for (int d = 0; d < ND; ++d) pom[myq*ND + d] = pfin[d];
    }
    {
        const int slot = (tid < 128) ? 0 : 1;
        const int t = (tid < 128) ? tid : tid - 128;
        const bool doSlot = (slot == 0) || !joined;
        const int bd2 = slot ? s1 : s0;
        float* fob = out + (size_t)nBoards * (CELLS * ND) + (size_t)bd2 * (CELLS * ND);
        if (doSlot) {
            for (int i = t; i < CELLS * ND; i += 128) {
                int q = i / ND, d = i - q * ND;
                fob[i] = (digit[slot][q] == d) ? 1.f : 0.f;
            }
        }
    }
}

extern "C" void kernel_launch(void* const* d_in, const int* in_sizes, int n_in,
                              void* d_out, int out_size, void* d_ws, size_t ws_size,
                              hipStream_t stream) {
    const float* x  = (const float*)d_in[0];
    // d_in[1] is the constraint mask c — structurally known, not needed.
    const float* W1 = (const float*)d_in[2];
    const float* W2 = (const float*)d_in[3];
    float* out = (float*)d_out;
    float* ws  = (float*)d_ws;
    int nBoards = in_sizes[0] / (CELLS * ND);
    int* cnts   = (int*)ws + CNT_OFF;
    int* ordArr = (int*)ws + ORD_OFF;
    hipMemsetAsync(cnts, 0, 2 * sizeof(int), stream);
    hipMemsetAsync(ordArr, 0xFF, 2 * NBLK * sizeof(int), stream);
    int prepBlocks = (nBoards > 194) ? nBoards : 194;   // tables need 194 blocks
    prep_kernel<<<prepBlocks, 64, 0, stream>>>(x, W1, W2, ws, cnts, ordArr, nBoards);
    sudoku_kernel<<<NBLK, 256, 0, stream>>>(x, ws, ordArr, out, nBoards);
}

// Round 17
// 147.525 us; speedup vs baseline: 1.0648x; 1.0548x over previous
//
#include <hip/hip_runtime.h>

#define CELLS 81
#define ND 9
#define HID 100
#define NP 52    // padded unit-pairs: 50 real + 2 zero
#define PPW 13   // pairs per wave (4 waves x 13 = 52)
#define NREG 8   // W2 pairs persisted in VGPRs per wave (rest via LDS)

typedef float v2f __attribute__((ext_vector_type(2)));

#define W1P_SZ (9 * NP * 8)           // 3744 floats: [d][pair]{A0,A1,B0,B1,C0,C1,0,0}
#define W2P_OFF W1P_SZ                // 3744
#define W2P_SZ (NP * 20)              // 1040 floats: [pair]{d0u0,d0u1,...,d8u0,d8u1,0,0}
#define CNT_OFF (W2P_OFF + W2P_SZ)    // 4784 (int words)
#define ORD_OFF (CNT_OFF + 2)
#define BIGSLOTS 64
#define SPILLSLOTS 8
#define NBLK (BIGSLOTS + 512 + SPILLSLOTS)   // 584 solver blocks

// One prolog kernel: packs weight tables (spread over first 75 blocks) and
// per-board empty-count + atomic two-region pairing into order[].
// cnts and order[] pre-memset to 0xFF (one hipMemsetAsync; counters start -1).
__global__ __launch_bounds__(64) void prep_kernel(
    const float* __restrict__ x_all,
    const float* __restrict__ W1, const float* __restrict__ W2,
    float* __restrict__ ws, int* __restrict__ cnts, int* __restrict__ order,
    int nBoards)
{
    const int b = blockIdx.x, t = threadIdx.x;
    const int gid = b * 64 + t;

    // ---- packed-table build, parallel across blocks ----
    if (gid < W1P_SZ) {
        int i = gid >> 3, k = gid & 7;
        int d = i / NP, j = i - d * NP;
        float v = 0.f;
        if (j < 50 && k < 6) {
            int u = 2 * j + (k & 1);
            v = W1[u*27 + (k >> 1) * 9 + d];
        }
        ws[gid] = v;
    } else if (gid < CNT_OFF) {
        int f = gid - W2P_OFF;
        int j = f / 20, k = f - j * 20;
        float v = 0.f;
        if (j < 50 && k < 18) {
            int d = k >> 1, u = 2 * j + (k & 1);
            v = W2[d*HID + u];
        }
        ws[gid] = v;
    }

    if (b >= nBoards) return;

    // ---- per-board empty count ----
    const float* xb = x_all + (size_t)b * (CELLS * ND);
    float mx = 0.f;
    #pragma unroll
    for (int d = 0; d < ND; ++d) mx = fmaxf(mx, xb[t*ND + d]);
    bool e1 = (mx < 0.5f);
    bool e2 = false;
    if (t < CELLS - 64) {
        float m2 = 0.f;
        #pragma unroll
        for (int d = 0; d < ND; ++d) m2 = fmaxf(m2, xb[(64+t)*ND + d]);
        e2 = (m2 < 0.5f);
    }
    unsigned long long m1 = __ballot(e1), m2b = __ballot(e2);
    if (t == 0) {
        int ne = __popcll(m1) + __popcll(m2b);
        if (ne > 32) {                       // big: own joined block, region [0,64)+spill
            int p = atomicAdd(&cnts[0], 1) + 1;     // counter starts at -1
            int blk = (p < BIGSLOTS) ? p : (BIGSLOTS + 512 + (p - BIGSLOTS));
            if (blk < NBLK) { order[2*blk] = b; order[2*blk + 1] = b; }
        } else {                             // small: pair in region [64, 576)
            int p = atomicAdd(&cnts[1], 1) + 1;
            int blk = BIGSLOTS + (p >> 1);
            order[2*blk + (p & 1)] = b;
        }
    }
}

// R13-proven solver: 40.2 KB LDS -> 4 blocks/CU (the T-table variant's 57.9 KB
// halved occupancy to 2/CU and cost +38 us of latency exposure -- R16 lesson).
// W2 for NREG pairs in registers, loaded from LDS (R15 lesson: global-loaded
// uniforms get rematerialized as in-loop global loads at ~200cy).
__global__ __launch_bounds__(256, 2) void sudoku_kernel(
    const float* __restrict__ x_all,
    const float* __restrict__ ws,
    const int* __restrict__ order,
    float* __restrict__ out, int nBoards)
{
    const int tid = threadIdx.x;      // 4 waves x 13 pairs
    const int wv  = tid >> 6;
    const int lw  = tid & 63;
    const int h   = lw >> 5;          // 32-lane segment within wave
    const int jbase = wv * PPW;

    const int s0  = order[2 * blockIdx.x];
    const int s1r = order[2 * blockIdx.x + 1];
    if (s0 < 0) return;
    const int s1 = (s1r < 0) ? s0 : s1r;
    const bool joined = (s0 == s1);   // one 64-lane board (big or lone small)
    const int myBoard = h ? s1 : s0;
    const int idx = joined ? 0 : h;   // cnt/digit slot

    float* pom = out + (size_t)myBoard * (CELLS * ND);

    __shared__ __align__(16) float w1s[W1P_SZ];      // 14976 B
    __shared__ __align__(16) float w2s[W2P_SZ];      // 4160 B
    __shared__ float parts[2][4][ND][64];            // 18432 B, conflict-free layout
    __shared__ float cnt[2][3 * 81];                 // 1944 B
    __shared__ int   digit[2][CELLS];                // 648 B

    // ---- stage packed weights, zero counts ----
    for (int i = tid; i < W1P_SZ / 4; i += 256)
        ((float4*)w1s)[i] = ((const float4*)ws)[i];
    for (int i = tid; i < W2P_SZ / 4; i += 256)
        ((float4*)w2s)[i] = ((const float4*)(ws + W2P_OFF))[i];
    for (int i = tid; i < 2 * 243; i += 256) (&cnt[0][0])[i] = 0.f;
    __syncthreads();

    // ---- persist W2 for first NREG own pairs in registers (from LDS) ----
    float w2reg[NREG][18];
    #pragma unroll
    for (int j = 0; j < NREG; ++j) {
        const float* qq = &w2s[(jbase + j) * 20];
        #pragma unroll
        for (int k = 0; k < 18; ++k) w2reg[j][k] = qq[k];
    }

    // ---- per-slot digit scan + counts + po init ----
    {
        const int slot = (tid < 128) ? 0 : 1;
        const int t = (tid < 128) ? tid : tid - 128;
        const bool doSlot = (slot == 0) || !joined;
        const int bd = slot ? s1 : s0;
        const float* xb = x_all + (size_t)bd * (CELLS * ND);
        float* pob = out + (size_t)bd * (CELLS * ND);
        if (doSlot) {
            if (t < CELLS) {
                int dig = -1;
                #pragma unroll
                for (int d = 0; d < ND; ++d)
                    if (dig < 0 && xb[t*ND + d] > 0.5f) dig = d;
                digit[slot][t] = dig;
                if (dig >= 0) {
                    int r = t/9, c = t%9, b = (r/3)*3 + c/3;
                    atomicAdd(&cnt[slot][r*9 + dig], 1.f);
                    atomicAdd(&cnt[slot][81 + c*9 + dig], 1.f);
                    atomicAdd(&cnt[slot][162 + b*9 + dig], 1.f);
                }
            }
            for (int i = t; i < CELLS * ND; i += 128) pob[i] = xb[i];
        }
    }
    __syncthreads();

    // ---- rank -> cell via digit scan; ne for both slots ----
    const int rank = joined ? lw : (lw & 31);
    int myq = 127;
    int ne0 = 0, ne1 = 0;
    for (int q = 0; q < CELLS; ++q)
        if (digit[0][q] < 0) { if (idx == 0 && ne0 == rank) myq = q; ++ne0; }
    if (!joined) {
        for (int q = 0; q < CELLS; ++q)
            if (digit[1][q] < 0) { if (idx == 1 && ne1 == rank) myq = q; ++ne1; }
    } else ne1 = ne0;
    if (ne0 > 64) ne0 = 64;
    if (ne1 > 64) ne1 = 64;
    const int ne_mine = idx ? ne1 : ne0;
    const int itMax = max(ne0, ne1);
    bool active = (rank < ne_mine);

    const int myr = (myq < 81) ? myq / 9 : 0;
    const int myc = (myq < 81) ? myq % 9 : 0;
    const int myb = (myr / 3) * 3 + myc / 3;

    // ---- z init: 27 counts in regs; own 13 pairs from packed W1 ----
    float crr[9], ccc[9], cbb[9];
    #pragma unroll
    for (int j = 0; j < 9; ++j) {
        crr[j] = cnt[idx][myr*9 + j];
        ccc[j] = cnt[idx][81 + myc*9 + j];
        cbb[j] = cnt[idx][162 + myb*9 + j];
    }
    v2f z2[PPW];
    #pragma unroll
    for (int j = 0; j < PPW; ++j) {
        v2f a = (v2f){0.f, 0.f};
        #pragma unroll
        for (int d = 0; d < 9; ++d) {
            const float* p = &w1s[(d*NP + jbase + j) * 8];
            float4 ab = *(const float4*)p;
            v2f Cv = *(const v2f*)(p + 4);
            v2f Av = (v2f){ab.x, ab.y}, Bv = (v2f){ab.z, ab.w};
            a += crr[d]*Av + ccc[d]*Bv + cbb[d]*Cv;
        }
        z2[j] = a;
    }

    int dc = 0;
    v2f b0v = (v2f){0.f,0.f}, b1v = (v2f){0.f,0.f}, b2v = (v2f){0.f,0.f};
    float pfin[ND];

    // ---- solve loop: 1 barrier/iter; W2 mostly from registers ----
    for (int it = 0; it < itMax; ++it) {
        const float* w1r = &w1s[(dc*NP + jbase) * 8];   // <=2 distinct addrs/wave
        const float* w2r = &w2s[jbase * 20];

        v2f acc2[ND];
        #pragma unroll
        for (int d = 0; d < ND; ++d) acc2[d] = (v2f){0.f, 0.f};

        #pragma unroll
        for (int j = 0; j < PPW; ++j) {
            const float* p = w1r + j*8;
            float4 ab = *(const float4*)p;
            v2f Cv = *(const v2f*)(p + 4);
            v2f Av = (v2f){ab.x, ab.y}, Bv = (v2f){ab.z, ab.w};
            v2f zv = z2[j];
            zv = b0v*Av + (b1v*Bv + (b2v*Cv + zv));
            z2[j] = zv;
            v2f hh;
            hh.x = fmaxf(zv.x, 0.f);
            hh.y = fmaxf(zv.y, 0.f);
            if (j < NREG) {
                #pragma unroll
                for (int d = 0; d < ND; ++d)
                    acc2[d] += hh * (v2f){w2reg[j][2*d], w2reg[j][2*d + 1]};
            } else {
                const float* qq = w2r + j*20;
                float4 w01 = *(const float4*)qq;
                float4 w23 = *(const float4*)(qq + 4);
                float4 w45 = *(const float4*)(qq + 8);
                float4 w67 = *(const float4*)(qq + 12);
                v2f w8 = *(const v2f*)(qq + 16);
                acc2[0] += hh * (v2f){w01.x, w01.y};
                acc2[1] += hh * (v2f){w01.z, w01.w};
                acc2[2] += hh * (v2f){w23.x, w23.y};
                acc2[3] += hh * (v2f){w23.z, w23.w};
                acc2[4] += hh * (v2f){w45.x, w45.y};
                acc2[5] += hh * (v2f){w45.z, w45.w};
                acc2[6] += hh * (v2f){w67.x, w67.y};
                acc2[7] += hh * (v2f){w67.z, w67.w};
                acc2[8] += hh * w8;
            }
        }

        const int buf = it & 1;
        #pragma unroll
        for (int d = 0; d < ND; ++d)
            parts[buf][wv][d][lw] = acc2[d].x + acc2[d].y;
        __syncthreads();

        // combine in fixed wave order 0..3 -> bit-identical in all waves
        float acc[ND];
        #pragma unroll
        for (int d = 0; d < ND; ++d) acc[d] = parts[buf][0][d][lw];
        #pragma unroll
        for (int ow = 1; ow < 4; ++ow) {
            #pragma unroll
            for (int d = 0; d < ND; ++d) acc[d] += parts[buf][ow][d][lw];
        }

        // softmax + per-cell best digit (strict >: first max)
        float m9 = fmaxf(fmaxf(fmaxf(acc[0],acc[1]), fmaxf(acc[2],acc[3])),
                         fmaxf(fmaxf(acc[4],acc[5]), fmaxf(acc[6],acc[7])));
        m9 = fmaxf(m9, acc[8]);
        float s = 0.f;
        #pragma unroll
        for (int d = 0; d < ND; ++d) { acc[d] = __expf(acc[d] - m9); s += acc[d]; }
        float inv = 1.f / s;
        float bv = -1.f; int bd = 0;
        #pragma unroll
        for (int d = 0; d < ND; ++d) {
            acc[d] *= inv;
            if (acc[d] > bv) { bv = acc[d]; bd = d; }
        }

        // per-segment winner: butterfly within 32 lanes (+1 round if joined)
        float bvv = active ? bv : -1.f;
        float vmax = bvv;
        #pragma unroll
        for (int off = 16; off >= 1; off >>= 1)
            vmax = fmaxf(vmax, __shfl_xor(vmax, off));
        if (joined) vmax = fmaxf(vmax, __shfl_xor(vmax, 32));
        const unsigned long long segMask =
            joined ? ~0ull : (h ? 0xFFFFFFFF00000000ull : 0x00000000FFFFFFFFull);
        unsigned long long msk = __ballot(active && (bvv == vmax)) & segMask;
        const bool valid = (msk != 0);
        int wl = valid ? (__ffsll(msk) - 1) : 0;   // lowest lane = lowest q
        int qw = __shfl(myq, wl);
        int dwn = __shfl(bd, wl);

        if (active && valid && myq == qw) {
            #pragma unroll
            for (int d = 0; d < ND; ++d) pfin[d] = acc[d];
            if (wv == 0) digit[idx][myq] = dwn;
            active = false;
        }
        const int pr = qw/9, pcc = qw%9, pb = (pr/3)*3 + pcc/3;
        b0v = (v2f)((valid && myr == pr)  ? 1.f : 0.f);
        b1v = (v2f)((valid && myc == pcc) ? 1.f : 0.f);
        b2v = (v2f)((valid && myb == pb)  ? 1.f : 0.f);
        if (valid) dc = dwn;
    }

    // ---- outputs ----
    __syncthreads();
    if (wv == 0 && myq < 81) {
        #pragma unroll
        for (int d = 0; d < ND; ++d) pom[myq*ND + d] = pfin[d];
    }
    {
        const int slot = (tid < 128) ? 0 : 1;
        const int t = (tid < 128) ? tid : tid - 128;
        const bool doSlot = (slot == 0) || !joined;
        const int bd2 = slot ? s1 : s0;
        float* fob = out + (size_t)nBoards * (CELLS * ND) + (size_t)bd2 * (CELLS * ND);
        if (doSlot) {
            for (int i = t; i < CELLS * ND; i += 128) {
                int q = i / ND, d = i - q * ND;
                fob[i] = (digit[slot][q] == d) ? 1.f : 0.f;
            }
        }
    }
}

extern "C" void kernel_launch(void* const* d_in, const int* in_sizes, int n_in,
                              void* d_out, int out_size, void* d_ws, size_t ws_size,
                              hipStream_t stream) {
    const float* x  = (const float*)d_in[0];
    // d_in[1] is the constraint mask c — structurally known, not needed.
    const float* W1 = (const float*)d_in[2];
    const float* W2 = (const float*)d_in[3];
    float* out = (float*)d_out;
    float* ws  = (float*)d_ws;
    int nBoards = in_sizes[0] / (CELLS * ND);
    int* cnts   = (int*)ws + CNT_OFF;
    int* ordArr = (int*)ws + ORD_OFF;
    // one memset: cnts -> -1 (counters start -1, atomicAdd+1 yields 0,1,2,...)
    // and order[] -> -1
    hipMemsetAsync(cnts, 0xFF, (2 + 2 * NBLK) * sizeof(int), stream);
    prep_kernel<<<nBoards, 64, 0, stream>>>(x, W1, W2, ws, cnts, ordArr, nBoards);
    sudoku_kernel<<<NBLK, 256, 0, stream>>>(x, ws, ordArr, out, nBoards);
}

// Round 18
// 135.776 us; speedup vs baseline: 1.1569x; 1.0865x over previous
//
#include <hip/hip_runtime.h>

#define CELLS 81
#define ND 9
#define HID 100
#define NP 52    // padded unit-pairs: 50 real + 2 zero
#define PPW 13   // pairs per wave (4 waves x 13 = 52)
#define NREG 8   // W2 pairs persisted in VGPRs per wave (rest via LDS)

typedef float v2f __attribute__((ext_vector_type(2)));

#define W1P_SZ (9 * NP * 8)           // 3744 floats
#define W2P_OFF W1P_SZ                // 3744
#define W2P_SZ (NP * 20)              // 1040 floats
#define BCNT_OFF (W2P_OFF + W2P_SZ)   // 4784: 65 bucket counters (int)
#define ORD_OFF (BCNT_OFF + 65)       // 4849: order[2*1024] (int)
#define SLOT_OFF (ORD_OFF + 2048)     // 6897: bucketSlot[65][256] (int)

// Prolog 1: pack weight tables (first 75 blocks' worth, folded in) and
// bucket each board by its empty-count (counting-sort phase 1).
// bcnt[] pre-memset to 0xFF (counters start -1); order[] pre-memset to -1.
__global__ __launch_bounds__(64) void prep_kernel(
    const float* __restrict__ x_all,
    const float* __restrict__ W1, const float* __restrict__ W2,
    float* __restrict__ ws, int* __restrict__ bcnt, int* __restrict__ slot,
    int nBoards)
{
    const int b = blockIdx.x, t = threadIdx.x;
    const int gid = b * 64 + t;

    if (gid < W1P_SZ) {
        int i = gid >> 3, k = gid & 7;
        int d = i / NP, j = i - d * NP;
        float v = 0.f;
        if (j < 50 && k < 6) {
            int u = 2 * j + (k & 1);
            v = W1[u*27 + (k >> 1) * 9 + d];
        }
        ws[gid] = v;
    } else if (gid < BCNT_OFF) {
        int f = gid - W2P_OFF;
        int j = f / 20, k = f - j * 20;
        float v = 0.f;
        if (j < 50 && k < 18) {
            int d = k >> 1, u = 2 * j + (k & 1);
            v = W2[d*HID + u];
        }
        ws[gid] = v;
    }

    if (b >= nBoards) return;

    const float* xb = x_all + (size_t)b * (CELLS * ND);
    float mx = 0.f;
    #pragma unroll
    for (int d = 0; d < ND; ++d) mx = fmaxf(mx, xb[t*ND + d]);
    bool e1 = (mx < 0.5f);
    bool e2 = false;
    if (t < CELLS - 64) {
        float m2 = 0.f;
        #pragma unroll
        for (int d = 0; d < ND; ++d) m2 = fmaxf(m2, xb[(64+t)*ND + d]);
        e2 = (m2 < 0.5f);
    }
    unsigned long long m1 = __ballot(e1), m2b = __ballot(e2);
    if (t == 0) {
        int ne = __popcll(m1) + __popcll(m2b);
        if (ne > 64) ne = 64;
        int r = atomicAdd(&bcnt[ne], 1) + 1;    // counter starts at -1
        if (r < 256) slot[ne * 256 + r] = b;
    }
}

// Prolog 2 (1 block): descending prefix over 65 buckets -> exact R13 order
// layout: bigs (ne>32) joined, one block each, in descending ne; smalls
// paired adjacent in sorted order (matched ne -> minimal lockstep waste).
__global__ __launch_bounds__(256) void scatter_kernel(
    const int* __restrict__ bcnt, const int* __restrict__ slot,
    int* __restrict__ order)
{
    __shared__ int base[66];
    __shared__ int cntS[65];
    __shared__ int nBigS;
    const int t = threadIdx.x;
    if (t < 65) cntS[t] = bcnt[t] + 1;          // -1 start -> count
    __syncthreads();
    if (t == 0) {
        int acc = 0, nb = 0;
        for (int ne = 64; ne >= 0; --ne) {      // descending ne
            base[ne] = acc;
            acc += cntS[ne];
            if (ne > 32) nb += cntS[ne];
        }
        nBigS = nb;
    }
    __syncthreads();
    const int nBig = nBigS;
    for (int ne = 64; ne >= 0; --ne) {
        const int c = cntS[ne];
        for (int r = t; r < c; r += 256) {
            int board = slot[ne * 256 + r];
            int pos = base[ne] + r;
            if (ne > 32) {                      // joined big: own block
                order[2*pos] = board; order[2*pos + 1] = board;
            } else {
                int rr = pos - nBig;
                int blk = nBig + (rr >> 1);
                order[2*blk + (rr & 1)] = board;
            }
        }
    }
}

// R13-proven solver: 40.4 KB LDS -> 4 blocks/CU. W2 for NREG pairs in
// registers, loaded from LDS (R15 lesson: global-loaded uniforms get
// rematerialized as in-loop global loads at ~200cy each).
__global__ __launch_bounds__(256, 2) void sudoku_kernel(
    const float* __restrict__ x_all,
    const float* __restrict__ ws,
    const int* __restrict__ order,
    float* __restrict__ out, int nBoards)
{
    const int tid = threadIdx.x;      // 4 waves x 13 pairs
    const int wv  = tid >> 6;
    const int lw  = tid & 63;
    const int h   = lw >> 5;          // 32-lane segment within wave
    const int jbase = wv * PPW;

    const int s0  = order[2 * blockIdx.x];
    const int s1r = order[2 * blockIdx.x + 1];
    if (s0 < 0) return;
    const int s1 = (s1r < 0) ? s0 : s1r;
    const bool joined = (s0 == s1);   // one 64-lane board (big or lone small)
    const int myBoard = h ? s1 : s0;
    const int idx = joined ? 0 : h;   // cnt/digit slot

    float* pom = out + (size_t)myBoard * (CELLS * ND);

    __shared__ __align__(16) float w1s[W1P_SZ];      // 14976 B
    __shared__ __align__(16) float w2s[W2P_SZ];      // 4160 B
    __shared__ float parts[2][4][ND][64];            // 18432 B, conflict-free
    __shared__ float cnt[2][3 * 81];                 // 1944 B
    __shared__ int   digit[2][CELLS];                // 648 B

    for (int i = tid; i < W1P_SZ / 4; i += 256)
        ((float4*)w1s)[i] = ((const float4*)ws)[i];
    for (int i = tid; i < W2P_SZ / 4; i += 256)
        ((float4*)w2s)[i] = ((const float4*)(ws + W2P_OFF))[i];
    for (int i = tid; i < 2 * 243; i += 256) (&cnt[0][0])[i] = 0.f;
    __syncthreads();

    float w2reg[NREG][18];
    #pragma unroll
    for (int j = 0; j < NREG; ++j) {
        const float* qq = &w2s[(jbase + j) * 20];
        #pragma unroll
        for (int k = 0; k < 18; ++k) w2reg[j][k] = qq[k];
    }

    {
        const int slot = (tid < 128) ? 0 : 1;
        const int t = (tid < 128) ? tid : tid - 128;
        const bool doSlot = (slot == 0) || !joined;
        const int bd = slot ? s1 : s0;
        const float* xb = x_all + (size_t)bd * (CELLS * ND);
        float* pob = out + (size_t)bd * (CELLS * ND);
        if (doSlot) {
            if (t < CELLS) {
                int dig = -1;
                #pragma unroll
                for (int d = 0; d < ND; ++d)
                    if (dig < 0 && xb[t*ND + d] > 0.5f) dig = d;
                digit[slot][t] = dig;
                if (dig >= 0) {
                    int r = t/9, c = t%9, b = (r/3)*3 + c/3;
                    atomicAdd(&cnt[slot][r*9 + dig], 1.f);
                    atomicAdd(&cnt[slot][81 + c*9 + dig], 1.f);
                    atomicAdd(&cnt[slot][162 + b*9 + dig], 1.f);
                }
            }
            for (int i = t; i < CELLS * ND; i += 128) pob[i] = xb[i];
        }
    }
    __syncthreads();

    const int rank = joined ? lw : (lw & 31);
    int myq = 127;
    int ne0 = 0, ne1 = 0;
    for (int q = 0; q < CELLS; ++q)
        if (digit[0][q] < 0) { if (idx == 0 && ne0 == rank) myq = q; ++ne0; }
    if (!joined) {
        for (int q = 0; q < CELLS; ++q)
            if (digit[1][q] < 0) { if (idx == 1 && ne1 == rank) myq = q; ++ne1; }
    } else ne1 = ne0;
    if (ne0 > 64) ne0 = 64;
    if (ne1 > 64) ne1 = 64;
    const int ne_mine = idx ? ne1 : ne0;
    const int itMax = max(ne0, ne1);
    bool active = (rank < ne_mine);

    const int myr = (myq < 81) ? myq / 9 : 0;
    const int myc = (myq < 81) ? myq % 9 : 0;
    const int myb = (myr / 3) * 3 + myc / 3;

    float crr[9], ccc[9], cbb[9];
    #pragma unroll
    for (int j = 0; j < 9; ++j) {
        crr[j] = cnt[idx][myr*9 + j];
        ccc[j] = cnt[idx][81 + myc*9 + j];
        cbb[j] = cnt[idx][162 + myb*9 + j];
    }
    v2f z2[PPW];
    #pragma unroll
    for (int j = 0; j < PPW; ++j) {
        v2f a = (v2f){0.f, 0.f};
        #pragma unroll
        for (int d = 0; d < 9; ++d) {
            const float* p = &w1s[(d*NP + jbase + j) * 8];
            float4 ab = *(const float4*)p;
            v2f Cv = *(const v2f*)(p + 4);
            v2f Av = (v2f){ab.x, ab.y}, Bv = (v2f){ab.z, ab.w};
            a += crr[d]*Av + ccc[d]*Bv + cbb[d]*Cv;
        }
        z2[j] = a;
    }

    int dc = 0;
    v2f b0v = (v2f){0.f,0.f}, b1v = (v2f){0.f,0.f}, b2v = (v2f){0.f,0.f};
    float pfin[ND];

    for (int it = 0; it < itMax; ++it) {
        const float* w1r = &w1s[(dc*NP + jbase) * 8];   // <=2 distinct addrs/wave
        const float* w2r = &w2s[jbase * 20];

        v2f acc2[ND];
        #pragma unroll
        for (int d = 0; d < ND; ++d) acc2[d] = (v2f){0.f, 0.f};

        #pragma unroll
        for (int j = 0; j < PPW; ++j) {
            const float* p = w1r + j*8;
            float4 ab = *(const float4*)p;
            v2f Cv = *(const v2f*)(p + 4);
            v2f Av = (v2f){ab.x, ab.y}, Bv = (v2f){ab.z, ab.w};
            v2f zv = z2[j];
            zv = b0v*Av + (b1v*Bv + (b2v*Cv + zv));
            z2[j] = zv;
            v2f hh;
            hh.x = fmaxf(zv.x, 0.f);
            hh.y = fmaxf(zv.y, 0.f);
            if (j < NREG) {
                #pragma unroll
                for (int d = 0; d < ND; ++d)
                    acc2[d] += hh * (v2f){w2reg[j][2*d], w2reg[j][2*d + 1]};
            } else {
                const float* qq = w2r + j*20;
                float4 w01 = *(const float4*)qq;
                float4 w23 = *(const float4*)(qq + 4);
                float4 w45 = *(const float4*)(qq + 8);
                float4 w67 = *(const float4*)(qq + 12);
                v2f w8 = *(const v2f*)(qq + 16);
                acc2[0] += hh * (v2f){w01.x, w01.y};
                acc2[1] += hh * (v2f){w01.z, w01.w};
                acc2[2] += hh * (v2f){w23.x, w23.y};
                acc2[3] += hh * (v2f){w23.z, w23.w};
                acc2[4] += hh * (v2f){w45.x, w45.y};
                acc2[5] += hh * (v2f){w45.z, w45.w};
                acc2[6] += hh * (v2f){w67.x, w67.y};
                acc2[7] += hh * (v2f){w67.z, w67.w};
                acc2[8] += hh * w8;
            }
        }

        const int buf = it & 1;
        #pragma unroll
        for (int d = 0; d < ND; ++d)
            parts[buf][wv][d][lw] = acc2[d].x + acc2[d].y;
        __syncthreads();

        float acc[ND];
        #pragma unroll
        for (int d = 0; d < ND; ++d) acc[d] = parts[buf][0][d][lw];
        #pragma unroll
        for (int ow = 1; ow < 4; ++ow) {
            #pragma unroll
            for (int d = 0; d < ND; ++d) acc[d] += parts[buf][ow][d][lw];
        }

        float m9 = fmaxf(fmaxf(fmaxf(acc[0],acc[1]), fmaxf(acc[2],acc[3])),
                         fmaxf(fmaxf(acc[4],acc[5]), fmaxf(acc[6],acc[7])));
        m9 = fmaxf(m9, acc[8]);
        float s = 0.f;
        #pragma unroll
        for (int d = 0; d < ND; ++d) { acc[d] = __expf(acc[d] - m9); s += acc[d]; }
        float inv = 1.f / s;
        float bv = -1.f; int bd = 0;
        #pragma unroll
        for (int d = 0; d < ND; ++d) {
            acc[d] *= inv;
            if (acc[d] > bv) { bv = acc[d]; bd = d; }
        }

        float bvv = active ? bv : -1.f;
        float vmax = bvv;
        #pragma unroll
        for (int off = 16; off >= 1; off >>= 1)
            vmax = fmaxf(vmax, __shfl_xor(vmax, off));
        if (joined) vmax = fmaxf(vmax, __shfl_xor(vmax, 32));
        const unsigned long long segMask =
            joined ? ~0ull : (h ? 0xFFFFFFFF00000000ull : 0x00000000FFFFFFFFull);
        unsigned long long msk = __ballot(active && (bvv == vmax)) & segMask;
        const bool valid = (msk != 0);
        int wl = valid ? (__ffsll(msk) - 1) : 0;   // lowest lane = lowest q
        int qw = __shfl(myq, wl);
        int dwn = __shfl(bd, wl);

        if (active && valid && myq == qw) {
            #pragma unroll
            for (int d = 0; d < ND; ++d) pfin[d] = acc[d];
            if (wv == 0) digit[idx][myq] = dwn;
            active = false;
        }
        const int pr = qw/9, pcc = qw%9, pb = (pr/3)*3 + pcc/3;
        b0v = (v2f)((valid && myr == pr)  ? 1.f : 0.f);
        b1v = (v2f)((valid && myc == pcc) ? 1.f : 0.f);
        b2v = (v2f)((valid && myb == pb)  ? 1.f : 0.f);
        if (valid) dc = dwn;
    }

    __syncthreads();
    if (wv == 0 && myq < 81) {
        #pragma unroll
        for (int d = 0; d < ND; ++d) pom[myq*ND + d] = pfin[d];
    }
    {
        const int slot = (tid < 128) ? 0 : 1;
        const int t = (tid < 128) ? tid : tid - 128;
        const bool doSlot = (slot == 0) || !joined;
        const int bd2 = slot ? s1 : s0;
        float* fob = out + (size_t)nBoards * (CELLS * ND) + (size_t)bd2 * (CELLS * ND);
        if (doSlot) {
            for (int i = t; i < CELLS * ND; i += 128) {
                int q = i / ND, d = i - q * ND;
                fob[i] = (digit[slot][q] == d) ? 1.f : 0.f;
            }
        }
    }
}

extern "C" void kernel_launch(void* const* d_in, const int* in_sizes, int n_in,
                              void* d_out, int out_size, void* d_ws, size_t ws_size,
                              hipStream_t stream) {
    const float* x  = (const float*)d_in[0];
    // d_in[1] is the constraint mask c — structurally known, not needed.
    const float* W1 = (const float*)d_in[2];
    const float* W2 = (const float*)d_in[3];
    float* out = (float*)d_out;
    float* ws  = (float*)d_ws;
    int nBoards = in_sizes[0] / (CELLS * ND);
    int* bcnt   = (int*)ws + BCNT_OFF;
    int* ordArr = (int*)ws + ORD_OFF;
    int* slot   = (int*)ws + SLOT_OFF;
    // one memset: bcnt -> -1 (atomicAdd+1 yields 0-based ranks), order -> -1
    hipMemsetAsync(bcnt, 0xFF, (65 + 2048) * sizeof(int), stream);
    prep_kernel<<<nBoards, 64, 0, stream>>>(x, W1, W2, ws, bcnt, slot, nBoards);
    scatter_kernel<<<1, 256, 0, stream>>>(bcnt, slot, ordArr);
    sudoku_kernel<<<nBoards, 256, 0, stream>>>(x, ws, ordArr, out, nBoards);
}

// Round 19
// 123.519 us; speedup vs baseline: 1.2717x; 1.0992x over previous
//
#include <hip/hip_runtime.h>

#define CELLS 81
#define ND 9
#define HID 100
#define NP 52    // padded unit-pairs: 50 real + 2 zero
#define PPW 13   // pairs per wave (4 waves x 13 = 52)
#define NREG 8   // W2 pairs persisted in VGPRs per wave (rest via LDS)

typedef float v2f __attribute__((ext_vector_type(2)));

#define W1P_SZ (9 * NP * 8)           // 3744 floats
#define W2P_OFF W1P_SZ                // 3744
#define W2P_SZ (NP * 20)              // 1040 floats
#define BCNT_OFF (W2P_OFF + W2P_SZ)   // 4784: 65 bucket counters (int)
#define ORD_OFF (BCNT_OFF + 65)       // 4849: order[2*1024] (int)
#define SLOT_OFF (ORD_OFF + 2048)     // 6897: bucketSlot[65][256] (int)

// Prolog 1: pack weight tables (first 75 blocks' worth, folded in) and
// bucket each board by its empty-count (counting-sort phase 1).
// bcnt[] and order[] pre-memset to 0xFF (counters start -1).
__global__ __launch_bounds__(64) void prep_kernel(
    const float* __restrict__ x_all,
    const float* __restrict__ W1, const float* __restrict__ W2,
    float* __restrict__ ws, int* __restrict__ bcnt, int* __restrict__ slot,
    int nBoards)
{
    const int b = blockIdx.x, t = threadIdx.x;
    const int gid = b * 64 + t;

    if (gid < W1P_SZ) {
        int i = gid >> 3, k = gid & 7;
        int d = i / NP, j = i - d * NP;
        float v = 0.f;
        if (j < 50 && k < 6) {
            int u = 2 * j + (k & 1);
            v = W1[u*27 + (k >> 1) * 9 + d];
        }
        ws[gid] = v;
    } else if (gid < BCNT_OFF) {
        int f = gid - W2P_OFF;
        int j = f / 20, k = f - j * 20;
        float v = 0.f;
        if (j < 50 && k < 18) {
            int d = k >> 1, u = 2 * j + (k & 1);
            v = W2[d*HID + u];
        }
        ws[gid] = v;
    }

    if (b >= nBoards) return;

    const float* xb = x_all + (size_t)b * (CELLS * ND);
    float mx = 0.f;
    #pragma unroll
    for (int d = 0; d < ND; ++d) mx = fmaxf(mx, xb[t*ND + d]);
    bool e1 = (mx < 0.5f);
    bool e2 = false;
    if (t < CELLS - 64) {
        float m2 = 0.f;
        #pragma unroll
        for (int d = 0; d < ND; ++d) m2 = fmaxf(m2, xb[(64+t)*ND + d]);
        e2 = (m2 < 0.5f);
    }
    unsigned long long m1 = __ballot(e1), m2b = __ballot(e2);
    if (t == 0) {
        int ne = __popcll(m1) + __popcll(m2b);
        if (ne > 64) ne = 64;
        int r = atomicAdd(&bcnt[ne], 1) + 1;    // counter starts at -1
        if (r < 256) slot[ne * 256 + r] = b;
    }
}

// Prolog 2: 65 blocks, one per ne-bucket -- every block redundantly computes
// the descending-prefix base (cheap) then scatters its own bucket in one
// parallel pass. (R18 lesson: the 1-block serial-bucket walk cost ~18 us of
// dependent global latency while 255 CUs idled.)
__global__ __launch_bounds__(256) void scatter_kernel(
    const int* __restrict__ bcnt, const int* __restrict__ slot,
    int* __restrict__ order)
{
    __shared__ int cntS[65];
    __shared__ int baseS, nBigS;
    const int t = threadIdx.x;
    const int ne = blockIdx.x;                  // this block's bucket
    if (t < 65) cntS[t] = bcnt[t] + 1;          // -1 start -> count
    __syncthreads();
    if (t == 0) {
        int acc = 0, nb = 0;
        for (int k = 64; k > ne; --k) acc += cntS[k];   // boards with larger ne
        for (int k = 64; k > 32; --k) nb  += cntS[k];
        baseS = acc; nBigS = nb;
    }
    __syncthreads();
    int c = cntS[ne];
    if (c > 256) c = 256;
    const int base = baseS, nBig = nBigS;
    if (t < c) {
        int board = slot[ne * 256 + t];
        int pos = base + t;
        if (ne > 32) {                          // joined big: own block
            order[2*pos] = board; order[2*pos + 1] = board;
        } else {
            int rr = pos - nBig;
            int blk = nBig + (rr >> 1);
            order[2*blk + (rr & 1)] = board;
        }
    }
}

// R13-proven solver: 40.4 KB LDS -> 4 blocks/CU. W2 for NREG pairs in
// registers, loaded from LDS (R15 lesson: global-loaded uniforms get
// rematerialized as in-loop global loads at ~200cy each).
__global__ __launch_bounds__(256, 2) void sudoku_kernel(
    const float* __restrict__ x_all,
    const float* __restrict__ ws,
    const int* __restrict__ order,
    float* __restrict__ out, int nBoards)
{
    const int tid = threadIdx.x;      // 4 waves x 13 pairs
    const int wv  = tid >> 6;
    const int lw  = tid & 63;
    const int h   = lw >> 5;          // 32-lane segment within wave
    const int jbase = wv * PPW;

    const int s0  = order[2 * blockIdx.x];
    const int s1r = order[2 * blockIdx.x + 1];
    if (s0 < 0) return;
    const int s1 = (s1r < 0) ? s0 : s1r;
    const bool joined = (s0 == s1);   // one 64-lane board (big or lone small)
    const int myBoard = h ? s1 : s0;
    const int idx = joined ? 0 : h;   // cnt/digit slot

    float* pom = out + (size_t)myBoard * (CELLS * ND);

    __shared__ __align__(16) float w1s[W1P_SZ];      // 14976 B
    __shared__ __align__(16) float w2s[W2P_SZ];      // 4160 B
    __shared__ float parts[2][4][ND][64];            // 18432 B, conflict-free
    __shared__ float cnt[2][3 * 81];                 // 1944 B
    __shared__ int   digit[2][CELLS];                // 648 B

    for (int i = tid; i < W1P_SZ / 4; i += 256)
        ((float4*)w1s)[i] = ((const float4*)ws)[i];
    for (int i = tid; i < W2P_SZ / 4; i += 256)
        ((float4*)w2s)[i] = ((const float4*)(ws + W2P_OFF))[i];
    for (int i = tid; i < 2 * 243; i += 256) (&cnt[0][0])[i] = 0.f;
    __syncthreads();

    float w2reg[NREG][18];
    #pragma unroll
    for (int j = 0; j < NREG; ++j) {
        const float* qq = &w2s[(jbase + j) * 20];
        #pragma unroll
        for (int k = 0; k < 18; ++k) w2reg[j][k] = qq[k];
    }

    {
        const int slot = (tid < 128) ? 0 : 1;
        const int t = (tid < 128) ? tid : tid - 128;
        const bool doSlot = (slot == 0) || !joined;
        const int bd = slot ? s1 : s0;
        const float* xb = x_all + (size_t)bd * (CELLS * ND);
        float* pob = out + (size_t)bd * (CELLS * ND);
        if (doSlot) {
            if (t < CELLS) {
                int dig = -1;
                #pragma unroll
                for (int d = 0; d < ND; ++d)
                    if (dig < 0 && xb[t*ND + d] > 0.5f) dig = d;
                digit[slot][t] = dig;
                if (dig >= 0) {
                    int r = t/9, c = t%9, b = (r/3)*3 + c/3;
                    atomicAdd(&cnt[slot][r*9 + dig], 1.f);
                    atomicAdd(&cnt[slot][81 + c*9 + dig], 1.f);
                    atomicAdd(&cnt[slot][162 + b*9 + dig], 1.f);
                }
            }
            for (int i = t; i < CELLS * ND; i += 128) pob[i] = xb[i];
        }
    }
    __syncthreads();

    const int rank = joined ? lw : (lw & 31);
    int myq = 127;
    int ne0 = 0, ne1 = 0;
    for (int q = 0; q < CELLS; ++q)
        if (digit[0][q] < 0) { if (idx == 0 && ne0 == rank) myq = q; ++ne0; }
    if (!joined) {
        for (int q = 0; q < CELLS; ++q)
            if (digit[1][q] < 0) { if (idx == 1 && ne1 == rank) myq = q; ++ne1; }
    } else ne1 = ne0;
    if (ne0 > 64) ne0 = 64;
    if (ne1 > 64) ne1 = 64;
    const int ne_mine = idx ? ne1 : ne0;
    const int itMax = max(ne0, ne1);
    bool active = (rank < ne_mine);

    const int myr = (myq < 81) ? myq / 9 : 0;
    const int myc = (myq < 81) ? myq % 9 : 0;
    const int myb = (myr / 3) * 3 + myc / 3;

    float crr[9], ccc[9], cbb[9];
    #pragma unroll
    for (int j = 0; j < 9; ++j) {
        crr[j] = cnt[idx][myr*9 + j];
        ccc[j] = cnt[idx][81 + myc*9 + j];
        cbb[j] = cnt[idx][162 + myb*9 + j];
    }
    v2f z2[PPW];
    #pragma unroll
    for (int j = 0; j < PPW; ++j) {
        v2f a = (v2f){0.f, 0.f};
        #pragma unroll
        for (int d = 0; d < 9; ++d) {
            const float* p = &w1s[(d*NP + jbase + j) * 8];
            float4 ab = *(const float4*)p;
            v2f Cv = *(const v2f*)(p + 4);
            v2f Av = (v2f){ab.x, ab.y}, Bv = (v2f){ab.z, ab.w};
            a += crr[d]*Av + ccc[d]*Bv + cbb[d]*Cv;
        }
        z2[j] = a;
    }

    int dc = 0;
    v2f b0v = (v2f){0.f,0.f}, b1v = (v2f){0.f,0.f}, b2v = (v2f){0.f,0.f};
    float pfin[ND];

    for (int it = 0; it < itMax; ++it) {
        const float* w1r = &w1s[(dc*NP + jbase) * 8];   // <=2 distinct addrs/wave
        const float* w2r = &w2s[jbase * 20];

        v2f acc2[ND];
        #pragma unroll
        for (int d = 0; d < ND; ++d) acc2[d] = (v2f){0.f, 0.f};

        #pragma unroll
        for (int j = 0; j < PPW; ++j) {
            const float* p = w1r + j*8;
            float4 ab = *(const float4*)p;
            v2f Cv = *(const v2f*)(p + 4);
            v2f Av = (v2f){ab.x, ab.y}, Bv = (v2f){ab.z, ab.w};
            v2f zv = z2[j];
            zv = b0v*Av + (b1v*Bv + (b2v*Cv + zv));
            z2[j] = zv;
            v2f hh;
            hh.x = fmaxf(zv.x, 0.f);
            hh.y = fmaxf(zv.y, 0.f);
            if (j < NREG) {
                #pragma unroll
                for (int d = 0; d < ND; ++d)
                    acc2[d] += hh * (v2f){w2reg[j][2*d], w2reg[j][2*d + 1]};
            } else {
                const float* qq = w2r + j*20;
                float4 w01 = *(const float4*)qq;
                float4 w23 = *(const float4*)(qq + 4);
                float4 w45 = *(const float4*)(qq + 8);
                float4 w67 = *(const float4*)(qq + 12);
                v2f w8 = *(const v2f*)(qq + 16);
                acc2[0] += hh * (v2f){w01.x, w01.y};
                acc2[1] += hh * (v2f){w01.z, w01.w};
                acc2[2] += hh * (v2f){w23.x, w23.y};
                acc2[3] += hh * (v2f){w23.z, w23.w};
                acc2[4] += hh * (v2f){w45.x, w45.y};
                acc2[5] += hh * (v2f){w45.z, w45.w};
                acc2[6] += hh * (v2f){w67.x, w67.y};
                acc2[7] += hh * (v2f){w67.z, w67.w};
                acc2[8] += hh * w8;
            }
        }

        const int buf = it & 1;
        #pragma unroll
        for (int d = 0; d < ND; ++d)
            parts[buf][wv][d][lw] = acc2[d].x + acc2[d].y;
        __syncthreads();

        float acc[ND];
        #pragma unroll
        for (int d = 0; d < ND; ++d) acc[d] = parts[buf][0][d][lw];
        #pragma unroll
        for (int ow = 1; ow < 4; ++ow) {
            #pragma unroll
            for (int d = 0; d < ND; ++d) acc[d] += parts[buf][ow][d][lw];
        }

        float m9 = fmaxf(fmaxf(fmaxf(acc[0],acc[1]), fmaxf(acc[2],acc[3])),
                         fmaxf(fmaxf(acc[4],acc[5]), fmaxf(acc[6],acc[7])));
        m9 = fmaxf(m9, acc[8]);
        float s = 0.f;
        #pragma unroll
        for (int d = 0; d < ND; ++d) { acc[d] = __expf(acc[d] - m9); s += acc[d]; }
        float inv = 1.f / s;
        float bv = -1.f; int bd = 0;
        #pragma unroll
        for (int d = 0; d < ND; ++d) {
            acc[d] *= inv;
            if (acc[d] > bv) { bv = acc[d]; bd = d; }
        }

        float bvv = active ? bv : -1.f;
        float vmax = bvv;
        #pragma unroll
        for (int off = 16; off >= 1; off >>= 1)
            vmax = fmaxf(vmax, __shfl_xor(vmax, off));
        if (joined) vmax = fmaxf(vmax, __shfl_xor(vmax, 32));
        const unsigned long long segMask =
            joined ? ~0ull : (h ? 0xFFFFFFFF00000000ull : 0x00000000FFFFFFFFull);
        unsigned long long msk = __ballot(active && (bvv == vmax)) & segMask;
        const bool valid = (msk != 0);
        int wl = valid ? (__ffsll(msk) - 1) : 0;   // lowest lane = lowest q
        int qw = __shfl(myq, wl);
        int dwn = __shfl(bd, wl);

        if (active && valid && myq == qw) {
            #pragma unroll
            for (int d = 0; d < ND; ++d) pfin[d] = acc[d];
            if (wv == 0) digit[idx][myq] = dwn;
            active = false;
        }
        const int pr = qw/9, pcc = qw%9, pb = (pr/3)*3 + pcc/3;
        b0v = (v2f)((valid && myr == pr)  ? 1.f : 0.f);
        b1v = (v2f)((valid && myc == pcc) ? 1.f : 0.f);
        b2v = (v2f)((valid && myb == pb)  ? 1.f : 0.f);
        if (valid) dc = dwn;
    }

    __syncthreads();
    if (wv == 0 && myq < 81) {
        #pragma unroll
        for (int d = 0; d < ND; ++d) pom[myq*ND + d] = pfin[d];
    }
    {
        const int slot = (tid < 128) ? 0 : 1;
        const int t = (tid < 128) ? tid : tid - 128;
        const bool doSlot = (slot == 0) || !joined;
        const int bd2 = slot ? s1 : s0;
        float* fob = out + (size_t)nBoards * (CELLS * ND) + (size_t)bd2 * (CELLS * ND);
        if (doSlot) {
            for (int i = t; i < CELLS * ND; i += 128) {
                int q = i / ND, d = i - q * ND;
                fob[i] = (digit[slot][q] == d) ? 1.f : 0.f;
            }
        }
    }
}

extern "C" void kernel_launch(void* const* d_in, const int* in_sizes, int n_in,
                              void* d_out, int out_size, void* d_ws, size_t ws_size,
                              hipStream_t stream) {
    const float* x  = (const float*)d_in[0];
    // d_in[1] is the constraint mask c — structurally known, not needed.
    const float* W1 = (const float*)d_in[2];
    const float* W2 = (const float*)d_in[3];
    float* out = (float*)d_out;
    float* ws  = (float*)d_ws;
    int nBoards = in_sizes[0] / (CELLS * ND);
    int* bcnt   = (int*)ws + BCNT_OFF;
    int* ordArr = (int*)ws + ORD_OFF;
    int* slot   = (int*)ws + SLOT_OFF;
    // one memset: bcnt -> -1 (atomicAdd+1 yields 0-based ranks), order -> -1
    hipMemsetAsync(bcnt, 0xFF, (65 + 2048) * sizeof(int), stream);
    prep_kernel<<<nBoards, 64, 0, stream>>>(x, W1, W2, ws, bcnt, slot, nBoards);
    scatter_kernel<<<65, 256, 0, stream>>>(bcnt, slot, ordArr);
    sudoku_kernel<<<nBoards, 256, 0, stream>>>(x, ws, ordArr, out, nBoards);
}

// Round 20
// 118.867 us; speedup vs baseline: 1.3215x; 1.0391x over previous
//
#include <hip/hip_runtime.h>

#define CELLS 81
#define ND 9
#define HID 100
#define NP 52    // padded unit-pairs: 50 real + 2 zero
#define PPW 13   // pairs per wave (4 waves x 13 = 52)
#define NREG 8   // W2 pairs persisted in VGPRs per wave (rest via LDS)

typedef float v2f __attribute__((ext_vector_type(2)));

#define W1P_SZ (9 * NP * 8)           // 3744 floats
#define W2P_OFF W1P_SZ                // 3744
#define W2P_SZ (NP * 20)              // 1040 floats
#define NE_OFF (W2P_OFF + W2P_SZ)     // 4784: ne_arr[1024] (int)
#define ORD_OFF (NE_OFF + 1024)       // 5808: order[2*1024] (int)

// Prolog 1: pack weight tables (first ~75 blocks' worth of gids) and write
// each board's empty-count to ne_arr[b]. NO atomics, NO memset dependency.
__global__ __launch_bounds__(64) void prep_kernel(
    const float* __restrict__ x_all,
    const float* __restrict__ W1, const float* __restrict__ W2,
    float* __restrict__ ws, int* __restrict__ ne_arr, int nBoards)
{
    const int b = blockIdx.x, t = threadIdx.x;
    const int gid = b * 64 + t;

    if (gid < W1P_SZ) {
        int i = gid >> 3, k = gid & 7;
        int d = i / NP, j = i - d * NP;
        float v = 0.f;
        if (j < 50 && k < 6) {
            int u = 2 * j + (k & 1);
            v = W1[u*27 + (k >> 1) * 9 + d];
        }
        ws[gid] = v;
    } else if (gid < NE_OFF) {
        int f = gid - W2P_OFF;
        int j = f / 20, k = f - j * 20;
        float v = 0.f;
        if (j < 50 && k < 18) {
            int d = k >> 1, u = 2 * j + (k & 1);
            v = W2[d*HID + u];
        }
        ws[gid] = v;
    }

    if (b >= nBoards) return;

    const float* xb = x_all + (size_t)b * (CELLS * ND);
    float mx = 0.f;
    #pragma unroll
    for (int d = 0; d < ND; ++d) mx = fmaxf(mx, xb[t*ND + d]);
    bool e1 = (mx < 0.5f);
    bool e2 = false;
    if (t < CELLS - 64) {
        float m2 = 0.f;
        #pragma unroll
        for (int d = 0; d < ND; ++d) m2 = fmaxf(m2, xb[(64+t)*ND + d]);
        e2 = (m2 < 0.5f);
    }
    unsigned long long m1 = __ballot(e1), m2b = __ballot(e2);
    if (t == 0) {
        int ne = __popcll(m1) + __popcll(m2b);
        if (ne > 64) ne = 64;
        ne_arr[b] = ne;
    }
}

// Prolog 2: deterministic atomic-free counting sort. 66 blocks: blocks 0..64
// each own one ne-bucket (emit members in board-id order via wave-0 ballot
// compaction); block 65 writes the -1 tail and odd-parity hole so EVERY
// order[] slot is written each replay (no memset needed). Layout identical
// to R13: bigs (ne>32) joined, descending ne; smalls paired adjacent.
__global__ __launch_bounds__(256) void scatter_kernel(
    const int* __restrict__ ne_arr, int* __restrict__ order, int nBoards)
{
    __shared__ int sh_ne[1024];
    __shared__ int cntS[65];
    __shared__ int baseS, nBigS, nUsedS, oddS;
    const int t = threadIdx.x;
    const int bk = blockIdx.x;

    for (int i = t; i < 1024; i += 256)
        sh_ne[i] = (i < nBoards) ? ne_arr[i] : -1;
    __syncthreads();
    if (t < 65) {
        int c = 0;
        for (int j = 0; j < 1024; ++j) c += (sh_ne[j] == t) ? 1 : 0;
        cntS[t] = c;
    }
    __syncthreads();

    if (bk < 65) {
        if (t == 0) {
            int acc = 0, nb = 0;
            for (int k = 64; k > bk; --k) acc += cntS[k];
            for (int k = 64; k > 32; --k) nb += cntS[k];
            baseS = acc; nBigS = nb;
        }
        __syncthreads();
        const int base = baseS, nBig = nBigS;
        if (t < 64) {                       // wave 0: ballot-compact members
            int r = 0;
            for (int chunk = 0; chunk < 16; ++chunk) {
                int i = chunk * 64 + t;
                bool m = (sh_ne[i] == bk);
                unsigned long long mk = __ballot(m);
                if (m) {
                    int rk = r + __popcll(mk & ((1ull << t) - 1ull));
                    int pos = base + rk;
                    if (bk > 32) {          // joined big: own block
                        order[2*pos] = i; order[2*pos + 1] = i;
                    } else {
                        int rr = pos - nBig;
                        int blk = nBig + (rr >> 1);
                        order[2*blk + (rr & 1)] = i;
                    }
                }
                r += __popcll(mk);
            }
        }
    } else {
        if (t == 0) {
            int nb = 0, ns = 0;
            for (int k = 64; k > 32; --k) nb += cntS[k];
            for (int k = 0; k <= 32; ++k) ns += cntS[k];
            nBigS = nb;
            nUsedS = nb + (ns + 1) / 2;
            oddS = ns & 1;
        }
        __syncthreads();
        const int nUsed = nUsedS;
        for (int i = nUsed + t; i < 1024; i += 256) {
            order[2*i] = -1; order[2*i + 1] = -1;
        }
        if (t == 0 && oddS && nUsed > 0)
            order[2*(nUsed - 1) + 1] = -1;  // lone small -> joined mode
    }
}

// R13-proven solver (byte-identical): 40.4 KB LDS -> 4 blocks/CU. W2 for
// NREG pairs in registers, loaded from LDS (R15 lesson: global-loaded
// uniforms get rematerialized as in-loop global loads at ~200cy each).
__global__ __launch_bounds__(256, 2) void sudoku_kernel(
    const float* __restrict__ x_all,
    const float* __restrict__ ws,
    const int* __restrict__ order,
    float* __restrict__ out, int nBoards)
{
    const int tid = threadIdx.x;      // 4 waves x 13 pairs
    const int wv  = tid >> 6;
    const int lw  = tid & 63;
    const int h   = lw >> 5;          // 32-lane segment within wave
    const int jbase = wv * PPW;

    const int s0  = order[2 * blockIdx.x];
    const int s1r = order[2 * blockIdx.x + 1];
    if (s0 < 0) return;
    const int s1 = (s1r < 0) ? s0 : s1r;
    const bool joined = (s0 == s1);   // one 64-lane board (big or lone small)
    const int myBoard = h ? s1 : s0;
    const int idx = joined ? 0 : h;   // cnt/digit slot

    float* pom = out + (size_t)myBoard * (CELLS * ND);

    __shared__ __align__(16) float w1s[W1P_SZ];      // 14976 B
    __shared__ __align__(16) float w2s[W2P_SZ];      // 4160 B
    __shared__ float parts[2][4][ND][64];            // 18432 B, conflict-free
    __shared__ float cnt[2][3 * 81];                 // 1944 B
    __shared__ int   digit[2][CELLS];                // 648 B

    for (int i = tid; i < W1P_SZ / 4; i += 256)
        ((float4*)w1s)[i] = ((const float4*)ws)[i];
    for (int i = tid; i < W2P_SZ / 4; i += 256)
        ((float4*)w2s)[i] = ((const float4*)(ws + W2P_OFF))[i];
    for (int i = tid; i < 2 * 243; i += 256) (&cnt[0][0])[i] = 0.f;
    __syncthreads();

    float w2reg[NREG][18];
    #pragma unroll
    for (int j = 0; j < NREG; ++j) {
        const float* qq = &w2s[(jbase + j) * 20];
        #pragma unroll
        for (int k = 0; k < 18; ++k) w2reg[j][k] = qq[k];
    }

    {
        const int slot = (tid < 128) ? 0 : 1;
        const int t = (tid < 128) ? tid : tid - 128;
        const bool doSlot = (slot == 0) || !joined;
        const int bd = slot ? s1 : s0;
        const float* xb = x_all + (size_t)bd * (CELLS * ND);
        float* pob = out + (size_t)bd * (CELLS * ND);
        if (doSlot) {
            if (t < CELLS) {
                int dig = -1;
                #pragma unroll
                for (int d = 0; d < ND; ++d)
                    if (dig < 0 && xb[t*ND + d] > 0.5f) dig = d;
                digit[slot][t] = dig;
                if (dig >= 0) {
                    int r = t/9, c = t%9, b = (r/3)*3 + c/3;
                    atomicAdd(&cnt[slot][r*9 + dig], 1.f);
                    atomicAdd(&cnt[slot][81 + c*9 + dig], 1.f);
                    atomicAdd(&cnt[slot][162 + b*9 + dig], 1.f);
                }
            }
            for (int i = t; i < CELLS * ND; i += 128) pob[i] = xb[i];
        }
    }
    __syncthreads();

    const int rank = joined ? lw : (lw & 31);
    int myq = 127;
    int ne0 = 0, ne1 = 0;
    for (int q = 0; q < CELLS; ++q)
        if (digit[0][q] < 0) { if (idx == 0 && ne0 == rank) myq = q; ++ne0; }
    if (!joined) {
        for (int q = 0; q < CELLS; ++q)
            if (digit[1][q] < 0) { if (idx == 1 && ne1 == rank) myq = q; ++ne1; }
    } else ne1 = ne0;
    if (ne0 > 64) ne0 = 64;
    if (ne1 > 64) ne1 = 64;
    const int ne_mine = idx ? ne1 : ne0;
    const int itMax = max(ne0, ne1);
    bool active = (rank < ne_mine);

    const int myr = (myq < 81) ? myq / 9 : 0;
    const int myc = (myq < 81) ? myq % 9 : 0;
    const int myb = (myr / 3) * 3 + myc / 3;

    float crr[9], ccc[9], cbb[9];
    #pragma unroll
    for (int j = 0; j < 9; ++j) {
        crr[j] = cnt[idx][myr*9 + j];
        ccc[j] = cnt[idx][81 + myc*9 + j];
        cbb[j] = cnt[idx][162 + myb*9 + j];
    }
    v2f z2[PPW];
    #pragma unroll
    for (int j = 0; j < PPW; ++j) {
        v2f a = (v2f){0.f, 0.f};
        #pragma unroll
        for (int d = 0; d < 9; ++d) {
            const float* p = &w1s[(d*NP + jbase + j) * 8];
            float4 ab = *(const float4*)p;
            v2f Cv = *(const v2f*)(p + 4);
            v2f Av = (v2f){ab.x, ab.y}, Bv = (v2f){ab.z, ab.w};
            a += crr[d]*Av + ccc[d]*Bv + cbb[d]*Cv;
        }
        z2[j] = a;
    }

    int dc = 0;
    v2f b0v = (v2f){0.f,0.f}, b1v = (v2f){0.f,0.f}, b2v = (v2f){0.f,0.f};
    float pfin[ND];

    for (int it = 0; it < itMax; ++it) {
        const float* w1r = &w1s[(dc*NP + jbase) * 8];   // <=2 distinct addrs/wave
        const float* w2r = &w2s[jbase * 20];

        v2f acc2[ND];
        #pragma unroll
        for (int d = 0; d < ND; ++d) acc2[d] = (v2f){0.f, 0.f};

        #pragma unroll
        for (int j = 0; j < PPW; ++j) {
            const float* p = w1r + j*8;
            float4 ab = *(const float4*)p;
            v2f Cv = *(const v2f*)(p + 4);
            v2f Av = (v2f){ab.x, ab.y}, Bv = (v2f){ab.z, ab.w};
            v2f zv = z2[j];
            zv = b0v*Av + (b1v*Bv + (b2v*Cv + zv));
            z2[j] = zv;
            v2f hh;
            hh.x = fmaxf(zv.x, 0.f);
            hh.y = fmaxf(zv.y, 0.f);
            if (j < NREG) {
                #pragma unroll
                for (int d = 0; d < ND; ++d)
                    acc2[d] += hh * (v2f){w2reg[j][2*d], w2reg[j][2*d + 1]};
            } else {
                const float* qq = w2r + j*20;
                float4 w01 = *(const float4*)qq;
                float4 w23 = *(const float4*)(qq + 4);
                float4 w45 = *(const float4*)(qq + 8);
                float4 w67 = *(const float4*)(qq + 12);
                v2f w8 = *(const v2f*)(qq + 16);
                acc2[0] += hh * (v2f){w01.x, w01.y};
                acc2[1] += hh * (v2f){w01.z, w01.w};
                acc2[2] += hh * (v2f){w23.x, w23.y};
                acc2[3] += hh * (v2f){w23.z, w23.w};
                acc2[4] += hh * (v2f){w45.x, w45.y};
                acc2[5] += hh * (v2f){w45.z, w45.w};
                acc2[6] += hh * (v2f){w67.x, w67.y};
                acc2[7] += hh * (v2f){w67.z, w67.w};
                acc2[8] += hh * w8;
            }
        }

        const int buf = it & 1;
        #pragma unroll
        for (int d = 0; d < ND; ++d)
            parts[buf][wv][d][lw] = acc2[d].x + acc2[d].y;
        __syncthreads();

        float acc[ND];
        #pragma unroll
        for (int d = 0; d < ND; ++d) acc[d] = parts[buf][0][d][lw];
        #pragma unroll
        for (int ow = 1; ow < 4; ++ow) {
            #pragma unroll
            for (int d = 0; d < ND; ++d) acc[d] += parts[buf][ow][d][lw];
        }

        float m9 = fmaxf(fmaxf(fmaxf(acc[0],acc[1]), fmaxf(acc[2],acc[3])),
                         fmaxf(fmaxf(acc[4],acc[5]), fmaxf(acc[6],acc[7])));
        m9 = fmaxf(m9, acc[8]);
        float s = 0.f;
        #pragma unroll
        for (int d = 0; d < ND; ++d) { acc[d] = __expf(acc[d] - m9); s += acc[d]; }
        float inv = 1.f / s;
        float bv = -1.f; int bd = 0;
        #pragma unroll
        for (int d = 0; d < ND; ++d) {
            acc[d] *= inv;
            if (acc[d] > bv) { bv = acc[d]; bd = d; }
        }

        float bvv = active ? bv : -1.f;
        float vmax = bvv;
        #pragma unroll
        for (int off = 16; off >= 1; off >>= 1)
            vmax = fmaxf(vmax, __shfl_xor(vmax, off));
        if (joined) vmax = fmaxf(vmax, __shfl_xor(vmax, 32));
        const unsigned long long segMask =
            joined ? ~0ull : (h ? 0xFFFFFFFF00000000ull : 0x00000000FFFFFFFFull);
        unsigned long long msk = __ballot(active && (bvv == vmax)) & segMask;
        const bool valid = (msk != 0);
        int wl = valid ? (__ffsll(msk) - 1) : 0;   // lowest lane = lowest q
        int qw = __shfl(myq, wl);
        int dwn = __shfl(bd, wl);

        if (active && valid && myq == qw) {
            #pragma unroll
            for (int d = 0; d < ND; ++d) pfin[d] = acc[d];
            if (wv == 0) digit[idx][myq] = dwn;
            active = false;
        }
        const int pr = qw/9, pcc = qw%9, pb = (pr/3)*3 + pcc/3;
        b0v = (v2f)((valid && myr == pr)  ? 1.f : 0.f);
        b1v = (v2f)((valid && myc == pcc) ? 1.f : 0.f);
        b2v = (v2f)((valid && myb == pb)  ? 1.f : 0.f);
        if (valid) dc = dwn;
    }

    __syncthreads();
    if (wv == 0 && myq < 81) {
        #pragma unroll
        for (int d = 0; d < ND; ++d) pom[myq*ND + d] = pfin[d];
    }
    {
        const int slot = (tid < 128) ? 0 : 1;
        const int t = (tid < 128) ? tid : tid - 128;
        const bool doSlot = (slot == 0) || !joined;
        const int bd2 = slot ? s1 : s0;
        float* fob = out + (size_t)nBoards * (CELLS * ND) + (size_t)bd2 * (CELLS * ND);
        if (doSlot) {
            for (int i = t; i < CELLS * ND; i += 128) {
                int q = i / ND, d = i - q * ND;
                fob[i] = (digit[slot][q] == d) ? 1.f : 0.f;
            }
        }
    }
}

extern "C" void kernel_launch(void* const* d_in, const int* in_sizes, int n_in,
                              void* d_out, int out_size, void* d_ws, size_t ws_size,
                              hipStream_t stream) {
    const float* x  = (const float*)d_in[0];
    // d_in[1] is the constraint mask c — structurally known, not needed.
    const float* W1 = (const float*)d_in[2];
    const float* W2 = (const float*)d_in[3];
    float* out = (float*)d_out;
    float* ws  = (float*)d_ws;
    int nBoards = in_sizes[0] / (CELLS * ND);
    int* neArr  = (int*)ws + NE_OFF;
    int* ordArr = (int*)ws + ORD_OFF;
    prep_kernel<<<nBoards, 64, 0, stream>>>(x, W1, W2, ws, neArr, nBoards);
    scatter_kernel<<<66, 256, 0, stream>>>(neArr, ordArr, nBoards);
    sudoku_kernel<<<nBoards, 256, 0, stream>>>(x, ws, ordArr, out, nBoards);
}